// Round 10
// baseline (382.926 us; speedup 1.0000x reference)
//
#include <hip/hip_runtime.h>
#include <hip/hip_bf16.h>
#include <math.h>

#define N_NODES 50000
#define N_EDGES 800000
#define ETOT (N_EDGES + N_NODES)   // 850000 with self loops

typedef __attribute__((ext_vector_type(8))) short short8;      // 8 bf16 (4 VGPRs)
typedef __attribute__((ext_vector_type(4))) float floatx4;
typedef __attribute__((ext_vector_type(2))) float f32x2;       // -> v_pk_* f32 ops

// bf16 (raw u16 pairs) -> f32 decode: 1 VALU op each
__device__ __forceinline__ float bf_lo(unsigned u) { return __uint_as_float(u << 16); }
__device__ __forceinline__ float bf_hi(unsigned u) { return __uint_as_float(u & 0xffff0000u); }
// f32 -> bf16 raw bits, RNE
__device__ __forceinline__ unsigned short f2bf(float f) {
    unsigned u = __float_as_uint(f);
    return (unsigned short)((u + 0x7fffu + ((u >> 16) & 1u)) >> 16);
}
__device__ __forceinline__ unsigned pack2bf(float a, float b) {
    return (unsigned)f2bf(a) | ((unsigned)f2bf(b) << 16);
}
// butterfly add via DPP (VALU pipe, no LDS): ctrl must be a literal
#define DPP_ADD(p, ctrl) \
    (p) += __int_as_float(__builtin_amdgcn_update_dpp(0, __float_as_int(p), (ctrl), 0xF, 0xF, true))

// ==== K1: weight prep (bf16 transpose/concat) + zero deg ====================
__global__ __launch_bounds__(256) void k_prep(const float* __restrict__ W1l,
                                              const float* __restrict__ W1r,
                                              const float* __restrict__ W2l,
                                              const float* __restrict__ W2r,
                                              unsigned short* __restrict__ Wt1,
                                              unsigned short* __restrict__ Wt2,
                                              int* __restrict__ deg) {
    const int b = blockIdx.x;
    if (b < 384) {
        const int idx = b * 256 + threadIdx.x;
        if (idx < 65536) {
            const int k = idx >> 9;          // 0..127
            const int n = idx & 511;         // 0..511
            const float v = (n < 256) ? W1l[k * 256 + n] : W1r[k * 256 + (n - 256)];
            Wt1[n * 128 + k] = f2bf(v);
        } else {
            const int j = idx - 65536;       // 0..32767
            const int k = j >> 7;            // 0..255
            const int n = j & 127;           // 0..127
            const float v = (n < 64) ? W2l[k * 64 + n] : W2r[k * 64 + (n - 64)];
            Wt2[n * 256 + k] = f2bf(v);
        }
    } else {
        const int i = (b - 384) * 256 + threadIdx.x;
        if (i < N_NODES) deg[i] = 0;
    }
}

// ==== K2: fused layer-1 MFMA projection (782 blocks) + dst histogram ========
__global__ __launch_bounds__(256) void k_g1h(const float* __restrict__ x,
                                             const unsigned short* __restrict__ Wt1,
                                             unsigned short* __restrict__ xlb,
                                             unsigned short* __restrict__ xrb,
                                             const int* __restrict__ ei,
                                             int* __restrict__ deg) {
    __shared__ unsigned short sA[128 * 136];
    const int b = blockIdx.x;
    if (b >= 782) {   // histogram path, grid-stride
        for (long e = (long)(b - 782) * 256 + threadIdx.x; e < ETOT; e += 1024 * 256) {
            const int d = (e < N_EDGES) ? ei[N_EDGES + e] : (int)(e - N_EDGES);
            atomicAdd(&deg[d], 1);
        }
        return;
    }
    const int t = threadIdx.x;
    const int lane = t & 63, wv = t >> 6;
    const int m0 = (b >> 1) * 128;
    const int flavor = b & 1;
#pragma unroll
    for (int j = 0; j < 16; j++) {
        const int i4 = t + j * 256;
        const int row = i4 >> 5, k4 = i4 & 31;
        float4 v = make_float4(0.f, 0.f, 0.f, 0.f);
        if (m0 + row < N_NODES) v = ((const float4*)x)[(long)(m0 + row) * 32 + k4];
        ushort4 u;
        u.x = f2bf(v.x); u.y = f2bf(v.y); u.z = f2bf(v.z); u.w = f2bf(v.w);
        *(ushort4*)&sA[row * 136 + k4 * 4] = u;
    }
    __syncthreads();
    const int l15 = lane & 15, quad = lane >> 4;
    const int nloc0 = wv * 64;
    unsigned short* outp = flavor ? xrb : xlb;
    short8 bfr[4][4];
#pragma unroll
    for (int nt = 0; nt < 4; nt++)
#pragma unroll
        for (int ks = 0; ks < 4; ks++)
            bfr[nt][ks] = *(const short8*)&Wt1[(flavor * 256 + nloc0 + nt * 16 + l15) * 128 + ks * 32 + quad * 8];
    for (int mt = 0; mt < 8; mt++) {
        short8 a[4];
#pragma unroll
        for (int ks = 0; ks < 4; ks++)
            a[ks] = *(const short8*)&sA[(mt * 16 + l15) * 136 + ks * 32 + quad * 8];
        floatx4 acc[4];
#pragma unroll
        for (int nt = 0; nt < 4; nt++) {
            acc[nt] = (floatx4)(0.f);
#pragma unroll
            for (int ks = 0; ks < 4; ks++)
                acc[nt] = __builtin_amdgcn_mfma_f32_16x16x32_bf16(a[ks], bfr[nt][ks], acc[nt], 0, 0, 0);
        }
        const int mrow0 = m0 + mt * 16 + quad * 4;
#pragma unroll
        for (int nt = 0; nt < 4; nt++) {
            const int n = nloc0 + nt * 16 + l15;
#pragma unroll
            for (int r = 0; r < 4; r++) {
                const int m = mrow0 + r;
                if (m < N_NODES) outp[(long)m * 256 + n] = f2bf(acc[nt][r]);
            }
        }
    }
}

// ==== K3: single-block exclusive scan over 50k degrees ======================
__global__ __launch_bounds__(1024) void k_scan(const int* __restrict__ deg,
                                               int* __restrict__ rowstart,
                                               int* __restrict__ cursor) {
    __shared__ int wsum[16];
    __shared__ int carry;
    const int t = threadIdx.x, lane = t & 63, wv = t >> 6;
    if (t == 0) carry = 0;
    __syncthreads();
    for (int base = 0; base < N_NODES; base += 1024) {
        const int i = base + t;
        const int v = (i < N_NODES) ? deg[i] : 0;
        int incl = v;
#pragma unroll
        for (int off = 1; off < 64; off <<= 1) {
            const int u = __shfl_up(incl, off);
            if (lane >= off) incl += u;
        }
        if (lane == 63) wsum[wv] = incl;
        __syncthreads();
        int woff = 0;
#pragma unroll
        for (int j = 0; j < 16; j++) woff += (j < wv) ? wsum[j] : 0;
        const int excl = incl - v + woff + carry;
        if (i < N_NODES) { rowstart[i] = excl; cursor[i] = excl; }
        __syncthreads();
        if (t == 0) {
            int tot = 0;
#pragma unroll
            for (int j = 0; j < 16; j++) tot += wsum[j];
            carry += tot;
        }
        __syncthreads();
    }
}

// ==== K4: scatter src ids into dst-grouped CSR slots ========================
__global__ __launch_bounds__(256) void k_scatter(const int* __restrict__ ei,
                                                 int* __restrict__ cursor,
                                                 int* __restrict__ csr) {
    const long e = (long)blockIdx.x * 256 + threadIdx.x;
    if (e >= ETOT) return;
    int s, d;
    if (e < N_EDGES) { s = ei[e]; d = ei[N_EDGES + e]; }
    else { s = d = (int)(e - N_EDGES); }
    const int pos = atomicAdd(&cursor[d], 1);
    csr[pos] = s;
}

// ==== K5: layer-1 fused node kernel: 2 edge-slots x 32 lanes, DPP reduce ====
__global__ __launch_bounds__(256) void k_node1(const int* __restrict__ rowstart,
                                               const int* __restrict__ deg,
                                               const int* __restrict__ csr,
                                               const uint4* __restrict__ xlb,   // bf16 row = 32 uint4
                                               const uint4* __restrict__ xrb,   // bf16 row = 32 uint4
                                               const float* __restrict__ att,   // [256]
                                               const float* __restrict__ b1,
                                               uint4* __restrict__ h1b) {      // bf16 row = 32 uint4
    const int lane = threadIdx.x & 63;
    const int wv = threadIdx.x >> 6;
    const int node = blockIdx.x * 4 + wv;   // 50000 % 4 == 0
    const int g = lane >> 5;                // edge slot
    const int l = lane & 31;                // covers elems 8l..8l+7
    const uint4 xru = xrb[(long)node * 32 + l];
    const float4 ta = ((const float4*)att)[2 * l];
    const float4 tb = ((const float4*)att)[2 * l + 1];
    f32x2 xp[4], tp[4];
    xp[0] = (f32x2){bf_lo(xru.x), bf_hi(xru.x)};
    xp[1] = (f32x2){bf_lo(xru.y), bf_hi(xru.y)};
    xp[2] = (f32x2){bf_lo(xru.z), bf_hi(xru.z)};
    xp[3] = (f32x2){bf_lo(xru.w), bf_hi(xru.w)};
    tp[0] = (f32x2){ta.x, ta.y}; tp[1] = (f32x2){ta.z, ta.w};
    tp[2] = (f32x2){tb.x, tb.y}; tp[3] = (f32x2){tb.z, tb.w};
    const int start = rowstart[node];
    const int cnt = deg[node];
    const int ns = (cnt - g + 1) >> 1;      // my slot's edge count
    float den = 0.f;
    f32x2 acc[4];
#pragma unroll
    for (int c = 0; c < 4; c++) acc[c] = (f32x2)(0.f);
    uint4 rcur = make_uint4(0, 0, 0, 0), rnext = rcur;
    if (ns > 0) rcur = xlb[(long)csr[start + g] * 32 + l];
    if (ns > 1) rnext = xlb[(long)csr[start + 2 + g] * 32 + l];
    for (int i = 0; i < ns; i++) {
        uint4 r2 = rcur;
        if (i + 2 < ns) r2 = xlb[(long)csr[start + 2 * (i + 2) + g] * 32 + l];
        f32x2 a0, a1, a2, a3;
        a0.x = bf_lo(rcur.x); a0.y = bf_hi(rcur.x);
        a1.x = bf_lo(rcur.y); a1.y = bf_hi(rcur.y);
        a2.x = bf_lo(rcur.z); a2.y = bf_hi(rcur.z);
        a3.x = bf_lo(rcur.w); a3.y = bf_hi(rcur.w);
        f32x2 v = a0 + xp[0];
        f32x2 p2 = __builtin_elementwise_max(v, v * 0.2f) * tp[0];
        v = a1 + xp[1]; p2 += __builtin_elementwise_max(v, v * 0.2f) * tp[1];
        v = a2 + xp[2]; p2 += __builtin_elementwise_max(v, v * 0.2f) * tp[2];
        v = a3 + xp[3]; p2 += __builtin_elementwise_max(v, v * 0.2f) * tp[3];
        float p = p2.x + p2.y;
        // butterfly over the 8-lane head group: xor1, xor2 (quad_perm), xor4 (half_mirror)
        DPP_ADD(p, 0xB1);    // quad_perm [1,0,3,2]
        DPP_ADD(p, 0x4E);    // quad_perm [2,3,0,1]
        DPP_ADD(p, 0x141);   // row_half_mirror (swap quads within 8)
        const float w = __expf(p);
        acc[0] += a0 * w;
        acc[1] += a1 * w;
        acc[2] += a2 * w;
        acc[3] += a3 * w;
        den += w;
        rcur = rnext; rnext = r2;
    }
    // combine across the 2 slots (lane <-> lane^32 hold the same elems)
    den += __shfl_xor(den, 32);
    const float inv = 1.f / (den + 1e-16f);
#pragma unroll
    for (int c = 0; c < 4; c++) {
        f32x2 t2 = acc[c];
        t2.x += __shfl_xor(t2.x, 32);
        t2.y += __shfl_xor(t2.y, 32);
        acc[c] = t2;
    }
    const float4 ba = ((const float4*)b1)[2 * l];
    const float4 bb = ((const float4*)b1)[2 * l + 1];
    f32x2 bp[4];
    bp[0] = (f32x2){ba.x, ba.y}; bp[1] = (f32x2){ba.z, ba.w};
    bp[2] = (f32x2){bb.x, bb.y}; bp[3] = (f32x2){bb.z, bb.w};
    float o[8];
#pragma unroll
    for (int c = 0; c < 4; c++) {
        f32x2 t2 = acc[c] * inv + bp[c];
        o[2 * c]     = t2.x > 0.f ? t2.x : expm1f(t2.x);
        o[2 * c + 1] = t2.y > 0.f ? t2.y : expm1f(t2.y);
    }
    if (g == 0) {
        uint4 u;
        u.x = pack2bf(o[0], o[1]);
        u.y = pack2bf(o[2], o[3]);
        u.z = pack2bf(o[4], o[5]);
        u.w = pack2bf(o[6], o[7]);
        h1b[(long)node * 32 + l] = u;
    }
}

// ==== K6: layer-2 MFMA projection: h1(bf16)[N,256] @ [W2l|W2r] ==============
__global__ __launch_bounds__(256) void k_gemm2(const uint4* __restrict__ h,   // bf16 rows
                                               const unsigned short* __restrict__ Wt2,
                                               unsigned short* __restrict__ xlb,
                                               unsigned short* __restrict__ xrb) {
    __shared__ unsigned short sA[64 * 264];
    const int t = threadIdx.x;
    const int lane = t & 63, wv = t >> 6;
    const int m0 = blockIdx.x * 64;
#pragma unroll
    for (int j = 0; j < 8; j++) {
        const int i8 = t + j * 256;          // 0..2047, 8 shorts each
        const int row = i8 >> 5, c8 = i8 & 31;
        uint4 v = make_uint4(0, 0, 0, 0);
        if (m0 + row < N_NODES) v = h[(long)(m0 + row) * 32 + c8];
        *(uint4*)&sA[row * 264 + c8 * 8] = v;
    }
    __syncthreads();
    const int l15 = lane & 15, quad = lane >> 4;
    const int ncol0 = wv * 32;
    short8 b[2][8];
#pragma unroll
    for (int nt = 0; nt < 2; nt++)
#pragma unroll
        for (int ks = 0; ks < 8; ks++)
            b[nt][ks] = *(const short8*)&Wt2[(ncol0 + nt * 16 + l15) * 256 + ks * 32 + quad * 8];
    for (int mt = 0; mt < 4; mt++) {
        floatx4 acc[2];
        acc[0] = (floatx4)(0.f);
        acc[1] = (floatx4)(0.f);
#pragma unroll
        for (int ks = 0; ks < 8; ks++) {
            const short8 a = *(const short8*)&sA[(mt * 16 + l15) * 264 + ks * 32 + quad * 8];
            acc[0] = __builtin_amdgcn_mfma_f32_16x16x32_bf16(a, b[0][ks], acc[0], 0, 0, 0);
            acc[1] = __builtin_amdgcn_mfma_f32_16x16x32_bf16(a, b[1][ks], acc[1], 0, 0, 0);
        }
        const int mrow0 = m0 + mt * 16 + quad * 4;
#pragma unroll
        for (int nt = 0; nt < 2; nt++) {
            const int n = ncol0 + nt * 16 + l15;
#pragma unroll
            for (int r = 0; r < 4; r++) {
                const int m = mrow0 + r;
                if (m < N_NODES) {
                    if (n < 64) xlb[(long)m * 64 + n] = f2bf(acc[nt][r]);
                    else        xrb[(long)m * 64 + (n - 64)] = f2bf(acc[nt][r]);
                }
            }
        }
    }
}

// ==== K7: layer-2 fused node kernel: 4 edge-slots x 16 lanes, DPP reduce ====
__global__ __launch_bounds__(256) void k_node2(const int* __restrict__ rowstart,
                                               const int* __restrict__ deg,
                                               const int* __restrict__ csr,
                                               const uint2* __restrict__ xlb,   // bf16 row = 16 uint2
                                               const uint2* __restrict__ xrb,   // bf16 row = 16 uint2
                                               const float* __restrict__ att,
                                               const float* __restrict__ b2,
                                               const float* __restrict__ Wlin,
                                               const float* __restrict__ blin,
                                               float* __restrict__ out) {
    __shared__ float sh[4][64];
    const int lane = threadIdx.x & 63;
    const int wv = threadIdx.x >> 6;
    const int node = blockIdx.x * 4 + wv;   // 50000 % 4 == 0
    const int g = lane >> 4;                // edge slot (0..3)
    const int l = lane & 15;                // covers elems 4l..4l+3
    const uint2 xru = xrb[(long)node * 16 + l];
    const float4 at4 = ((const float4*)att)[l];
    f32x2 xp[2], tp[2];
    xp[0] = (f32x2){bf_lo(xru.x), bf_hi(xru.x)};
    xp[1] = (f32x2){bf_lo(xru.y), bf_hi(xru.y)};
    tp[0] = (f32x2){at4.x, at4.y}; tp[1] = (f32x2){at4.z, at4.w};
    const int start = rowstart[node];
    const int cnt = deg[node];
    const int ns = (cnt - g + 3) >> 2;      // my slot's edge count (edges 4i+g)
    float den = 0.f;
    f32x2 acc[2];
    acc[0] = (f32x2)(0.f); acc[1] = (f32x2)(0.f);
    uint2 rcur = make_uint2(0, 0), rnext = rcur;
    if (ns > 0) rcur = xlb[(long)csr[start + g] * 16 + l];
    if (ns > 1) rnext = xlb[(long)csr[start + 4 + g] * 16 + l];
    for (int i = 0; i < ns; i++) {
        uint2 r2 = rcur;
        if (i + 2 < ns) r2 = xlb[(long)csr[start + 4 * (i + 2) + g] * 16 + l];
        f32x2 a0, a1;
        a0.x = bf_lo(rcur.x); a0.y = bf_hi(rcur.x);
        a1.x = bf_lo(rcur.y); a1.y = bf_hi(rcur.y);
        f32x2 v = a0 + xp[0];
        f32x2 p2 = __builtin_elementwise_max(v, v * 0.2f) * tp[0];
        v = a1 + xp[1]; p2 += __builtin_elementwise_max(v, v * 0.2f) * tp[1];
        float p = p2.x + p2.y;
        // butterfly over the 16-lane slot: xor1, xor2, xor4, xor8
        DPP_ADD(p, 0xB1);    // quad_perm [1,0,3,2]
        DPP_ADD(p, 0x4E);    // quad_perm [2,3,0,1]
        DPP_ADD(p, 0x141);   // row_half_mirror
        DPP_ADD(p, 0x140);   // row_mirror (swap 8-halves within 16)
        const float w = __expf(p);
        acc[0] += a0 * w;
        acc[1] += a1 * w;
        den += w;
        rcur = rnext; rnext = r2;
    }
    // combine across 4 slots (xor 16 then xor 32 align same elems)
    den += __shfl_xor(den, 16);
    den += __shfl_xor(den, 32);
    const float inv = 1.f / (den + 1e-16f);
    float t0 = acc[0].x, t1 = acc[0].y, t2 = acc[1].x, t3 = acc[1].y;
    t0 += __shfl_xor(t0, 16); t0 += __shfl_xor(t0, 32);
    t1 += __shfl_xor(t1, 16); t1 += __shfl_xor(t1, 32);
    t2 += __shfl_xor(t2, 16); t2 += __shfl_xor(t2, 32);
    t3 += __shfl_xor(t3, 16); t3 += __shfl_xor(t3, 32);
    const float4 b4 = ((const float4*)b2)[l];
    float4 h4;
    h4.x = t0 * inv + b4.x; h4.x = h4.x > 0.f ? h4.x : expm1f(h4.x);
    h4.y = t1 * inv + b4.y; h4.y = h4.y > 0.f ? h4.y : expm1f(h4.y);
    h4.z = t2 * inv + b4.z; h4.z = h4.z > 0.f ? h4.z : expm1f(h4.z);
    h4.w = t3 * inv + b4.w; h4.w = h4.w > 0.f ? h4.w : expm1f(h4.w);
    if (g == 0) ((float4*)sh[wv])[l] = h4;
    __syncthreads();
    float o = blin[lane];
#pragma unroll
    for (int k = 0; k < 64; k++) o = fmaf(sh[wv][k], Wlin[k * 64 + lane], o);
    out[(long)node * 64 + lane] = o;
}

extern "C" void kernel_launch(void* const* d_in, const int* in_sizes, int n_in,
                              void* d_out, int out_size, void* d_ws, size_t ws_size,
                              hipStream_t stream) {
    (void)in_sizes; (void)n_in; (void)out_size; (void)ws_size;
    const float* x    = (const float*)d_in[0];
    const int*   ei   = (const int*)d_in[1];
    const float* W1l  = (const float*)d_in[2];
    const float* W1r  = (const float*)d_in[3];
    const float* att1 = (const float*)d_in[4];
    const float* b1   = (const float*)d_in[5];
    const float* W2l  = (const float*)d_in[6];
    const float* W2r  = (const float*)d_in[7];
    const float* att2 = (const float*)d_in[8];
    const float* b2   = (const float*)d_in[9];
    const float* Wlin = (const float*)d_in[10];
    const float* blin = (const float*)d_in[11];

    float* ws = (float*)d_ws;
    unsigned short* XL1b = (unsigned short*)(ws);              // [N,256] bf16 (6.4M floats)
    unsigned short* XR1b = (unsigned short*)(ws + 6400000);    // [N,256] bf16
    uint4*          H1b  = (uint4*)(ws + 12800000);            // [N,256] bf16
    unsigned short* XL2b = (unsigned short*)(ws + 19200000);   // [N,64] bf16
    unsigned short* XR2b = (unsigned short*)(ws + 20800000);   // [N,64] bf16
    int* deg      = (int*)(ws + 22400000);  // 50,000
    int* rowstart = deg + 50000;            // 50,000
    int* cursor   = rowstart + 50000;       // 50,000
    int* csr      = cursor + 50000;         // 850,000 -> ends at 23,400,000 floats
    unsigned short* Wt1 = (unsigned short*)(ws + 23500000);    // 65,536 shorts -> ends 23,532,768 floats
    unsigned short* Wt2 = (unsigned short*)(ws + 23550000);    // 32,768 shorts (no overlap with Wt1)

    // K1: weight prep + zero deg
    k_prep<<<580, 256, 0, stream>>>(W1l, W1r, W2l, W2r, Wt1, Wt2, deg);
    // K2: gemm1 (782 blocks) fused with dst histogram (1024 blocks)
    k_g1h<<<1806, 256, 0, stream>>>(x, Wt1, XL1b, XR1b, ei, deg);
    // K3: exclusive scan -> rowstart + cursor
    k_scan<<<1, 1024, 0, stream>>>(deg, rowstart, cursor);
    // K4: scatter into CSR
    k_scatter<<<(ETOT + 255) / 256, 256, 0, stream>>>(ei, cursor, csr);
    // K5: layer-1 fused attention
    k_node1<<<12500, 256, 0, stream>>>(rowstart, deg, csr,
                                       (const uint4*)XL1b, (const uint4*)XR1b,
                                       att1, b1, H1b);
    // K6: layer-2 projection
    k_gemm2<<<782, 256, 0, stream>>>((const uint4*)H1b, Wt2, XL2b, XR2b);
    // K7: layer-2 fused attention + linear
    k_node2<<<12500, 256, 0, stream>>>(rowstart, deg, csr,
                                       (const uint2*)XL2b, (const uint2*)XR2b,
                                       att2, b2, Wlin, blin, (float*)d_out);
}

// Round 11
// 333.340 us; speedup vs baseline: 1.1488x; 1.1488x over previous
//
#include <hip/hip_runtime.h>
#include <hip/hip_bf16.h>
#include <math.h>

#define N_NODES 50000
#define N_EDGES 800000
#define ETOT (N_EDGES + N_NODES)   // 850000 with self loops
#define NB_SCAN 196                // ceil(50000/256)

typedef __attribute__((ext_vector_type(8))) short short8;      // 8 bf16 (4 VGPRs)
typedef __attribute__((ext_vector_type(4))) float floatx4;
typedef __attribute__((ext_vector_type(2))) float f32x2;       // -> v_pk_* f32 ops

// bf16 (raw u16 pairs) -> f32 decode: 1 VALU op each
__device__ __forceinline__ float bf_lo(unsigned u) { return __uint_as_float(u << 16); }
__device__ __forceinline__ float bf_hi(unsigned u) { return __uint_as_float(u & 0xffff0000u); }
// f32 -> bf16 raw bits, RNE
__device__ __forceinline__ unsigned short f2bf(float f) {
    unsigned u = __float_as_uint(f);
    return (unsigned short)((u + 0x7fffu + ((u >> 16) & 1u)) >> 16);
}
__device__ __forceinline__ unsigned pack2bf(float a, float b) {
    return (unsigned)f2bf(a) | ((unsigned)f2bf(b) << 16);
}
// butterfly add via DPP (VALU pipe, no LDS): ctrl must be a literal
#define DPP_ADD(p, ctrl) \
    (p) += __int_as_float(__builtin_amdgcn_update_dpp(0, __float_as_int(p), (ctrl), 0xF, 0xF, true))

// ==== K1: weight prep (bf16 transpose/concat) + zero deg ====================
__global__ __launch_bounds__(256) void k_prep(const float* __restrict__ W1l,
                                              const float* __restrict__ W1r,
                                              const float* __restrict__ W2l,
                                              const float* __restrict__ W2r,
                                              unsigned short* __restrict__ Wt1,
                                              unsigned short* __restrict__ Wt2,
                                              int* __restrict__ deg) {
    const int b = blockIdx.x;
    if (b < 384) {
        const int idx = b * 256 + threadIdx.x;
        if (idx < 65536) {
            const int k = idx >> 9;          // 0..127
            const int n = idx & 511;         // 0..511
            const float v = (n < 256) ? W1l[k * 256 + n] : W1r[k * 256 + (n - 256)];
            Wt1[n * 128 + k] = f2bf(v);
        } else {
            const int j = idx - 65536;       // 0..32767
            const int k = j >> 7;            // 0..255
            const int n = j & 127;           // 0..127
            const float v = (n < 64) ? W2l[k * 64 + n] : W2r[k * 64 + (n - 64)];
            Wt2[n * 256 + k] = f2bf(v);
        }
    } else {
        const int i = (b - 384) * 256 + threadIdx.x;
        if (i < N_NODES) deg[i] = 0;
    }
}

// ==== K2: fused layer-1 MFMA projection (782 blocks) + dst histogram ========
__global__ __launch_bounds__(256) void k_g1h(const float* __restrict__ x,
                                             const unsigned short* __restrict__ Wt1,
                                             unsigned short* __restrict__ xlb,
                                             unsigned short* __restrict__ xrb,
                                             const int* __restrict__ ei,
                                             int* __restrict__ deg) {
    __shared__ unsigned short sA[128 * 136];
    const int b = blockIdx.x;
    if (b >= 782) {   // histogram path, grid-stride
        for (long e = (long)(b - 782) * 256 + threadIdx.x; e < ETOT; e += 1024 * 256) {
            const int d = (e < N_EDGES) ? ei[N_EDGES + e] : (int)(e - N_EDGES);
            atomicAdd(&deg[d], 1);
        }
        return;
    }
    const int t = threadIdx.x;
    const int lane = t & 63, wv = t >> 6;
    const int m0 = (b >> 1) * 128;
    const int flavor = b & 1;
#pragma unroll
    for (int j = 0; j < 16; j++) {
        const int i4 = t + j * 256;
        const int row = i4 >> 5, k4 = i4 & 31;
        float4 v = make_float4(0.f, 0.f, 0.f, 0.f);
        if (m0 + row < N_NODES) v = ((const float4*)x)[(long)(m0 + row) * 32 + k4];
        ushort4 u;
        u.x = f2bf(v.x); u.y = f2bf(v.y); u.z = f2bf(v.z); u.w = f2bf(v.w);
        *(ushort4*)&sA[row * 136 + k4 * 4] = u;
    }
    __syncthreads();
    const int l15 = lane & 15, quad = lane >> 4;
    const int nloc0 = wv * 64;
    unsigned short* outp = flavor ? xrb : xlb;
    short8 bfr[4][4];
#pragma unroll
    for (int nt = 0; nt < 4; nt++)
#pragma unroll
        for (int ks = 0; ks < 4; ks++)
            bfr[nt][ks] = *(const short8*)&Wt1[(flavor * 256 + nloc0 + nt * 16 + l15) * 128 + ks * 32 + quad * 8];
    for (int mt = 0; mt < 8; mt++) {
        short8 a[4];
#pragma unroll
        for (int ks = 0; ks < 4; ks++)
            a[ks] = *(const short8*)&sA[(mt * 16 + l15) * 136 + ks * 32 + quad * 8];
        floatx4 acc[4];
#pragma unroll
        for (int nt = 0; nt < 4; nt++) {
            acc[nt] = (floatx4)(0.f);
#pragma unroll
            for (int ks = 0; ks < 4; ks++)
                acc[nt] = __builtin_amdgcn_mfma_f32_16x16x32_bf16(a[ks], bfr[nt][ks], acc[nt], 0, 0, 0);
        }
        const int mrow0 = m0 + mt * 16 + quad * 4;
#pragma unroll
        for (int nt = 0; nt < 4; nt++) {
            const int n = nloc0 + nt * 16 + l15;
#pragma unroll
            for (int r = 0; r < 4; r++) {
                const int m = mrow0 + r;
                if (m < N_NODES) outp[(long)m * 256 + n] = f2bf(acc[nt][r]);
            }
        }
    }
}

// ==== K3a/b/c: 3-pass parallel exclusive scan ===============================
__global__ __launch_bounds__(256) void k_scan1(const int* __restrict__ deg,
                                               int* __restrict__ rowstart,
                                               int* __restrict__ blocksum) {
    __shared__ int wsum[4];
    const int t = threadIdx.x, lane = t & 63, wv = t >> 6;
    const int i = blockIdx.x * 256 + t;
    const int v = (i < N_NODES) ? deg[i] : 0;
    int incl = v;
#pragma unroll
    for (int off = 1; off < 64; off <<= 1) {
        const int u = __shfl_up(incl, off);
        if (lane >= off) incl += u;
    }
    if (lane == 63) wsum[wv] = incl;
    __syncthreads();
    int woff = 0;
#pragma unroll
    for (int j = 0; j < 4; j++) woff += (j < wv) ? wsum[j] : 0;
    const int excl = incl - v + woff;
    if (i < N_NODES) rowstart[i] = excl;
    if (t == 255) blocksum[blockIdx.x] = excl + v;
}

__global__ __launch_bounds__(256) void k_scan2(const int* __restrict__ blocksum,
                                               int* __restrict__ blockoff) {
    __shared__ int wsum[4];
    const int t = threadIdx.x, lane = t & 63, wv = t >> 6;
    const int v = (t < NB_SCAN) ? blocksum[t] : 0;
    int incl = v;
#pragma unroll
    for (int off = 1; off < 64; off <<= 1) {
        const int u = __shfl_up(incl, off);
        if (lane >= off) incl += u;
    }
    if (lane == 63) wsum[wv] = incl;
    __syncthreads();
    int woff = 0;
#pragma unroll
    for (int j = 0; j < 4; j++) woff += (j < wv) ? wsum[j] : 0;
    if (t < NB_SCAN) blockoff[t] = incl - v + woff;
}

__global__ __launch_bounds__(256) void k_scan3(int* __restrict__ rowstart,
                                               const int* __restrict__ blockoff,
                                               int* __restrict__ cursor) {
    const int i = blockIdx.x * 256 + threadIdx.x;
    if (i < N_NODES) {
        const int r = rowstart[i] + blockoff[blockIdx.x];
        rowstart[i] = r;
        cursor[i] = r;
    }
}

// ==== K4: scatter BYTE OFFSETS (s*512) into dst-grouped CSR slots ===========
__global__ __launch_bounds__(256) void k_scatter(const int* __restrict__ ei,
                                                 int* __restrict__ cursor,
                                                 int* __restrict__ csr) {
    const long e = (long)blockIdx.x * 256 + threadIdx.x;
    if (e >= ETOT) return;
    int s, d;
    if (e < N_EDGES) { s = ei[e]; d = ei[N_EDGES + e]; }
    else { s = d = (int)(e - N_EDGES); }
    const int pos = atomicAdd(&cursor[d], 1);
    csr[pos] = s << 9;   // byte offset into 512B bf16 rows (layer1); layer2 = >>2
}

// ==== K5: layer-1 fused node kernel: 2 edge-slots x 32 lanes, DPP reduce ====
__global__ __launch_bounds__(256) void k_node1(const int* __restrict__ rowstart,
                                               const int* __restrict__ deg,
                                               const int* __restrict__ csr,
                                               const uint4* __restrict__ xlb,   // bf16 row = 32 uint4
                                               const uint4* __restrict__ xrb,   // bf16 row = 32 uint4
                                               const float* __restrict__ att,   // [256]
                                               const float* __restrict__ b1,
                                               uint4* __restrict__ h1b) {      // bf16 row = 32 uint4
    const int lane = threadIdx.x & 63;
    const int wv = threadIdx.x >> 6;
    const int node = blockIdx.x * 4 + wv;   // 50000 % 4 == 0
    const int g = lane >> 5;                // edge slot
    const int l = lane & 31;                // covers elems 8l..8l+7
    const char* xlbase = (const char*)xlb;
    const uint4 xru = xrb[(long)node * 32 + l];
    const float4 ta = ((const float4*)att)[2 * l];
    const float4 tb = ((const float4*)att)[2 * l + 1];
    f32x2 xp[4], tp[4];
    xp[0] = (f32x2){bf_lo(xru.x), bf_hi(xru.x)};
    xp[1] = (f32x2){bf_lo(xru.y), bf_hi(xru.y)};
    xp[2] = (f32x2){bf_lo(xru.z), bf_hi(xru.z)};
    xp[3] = (f32x2){bf_lo(xru.w), bf_hi(xru.w)};
    tp[0] = (f32x2){ta.x, ta.y}; tp[1] = (f32x2){ta.z, ta.w};
    tp[2] = (f32x2){tb.x, tb.y}; tp[3] = (f32x2){tb.z, tb.w};
    const int start = rowstart[node];
    const int cnt = deg[node];
    const int ns = (cnt - g + 1) >> 1;      // my slot's edge count
    float den = 0.f;
    f32x2 acc[4];
#pragma unroll
    for (int c = 0; c < 4; c++) acc[c] = (f32x2)(0.f);

    auto body = [&](const uint4& rr) {
        f32x2 a0, a1, a2, a3;
        a0.x = bf_lo(rr.x); a0.y = bf_hi(rr.x);
        a1.x = bf_lo(rr.y); a1.y = bf_hi(rr.y);
        a2.x = bf_lo(rr.z); a2.y = bf_hi(rr.z);
        a3.x = bf_lo(rr.w); a3.y = bf_hi(rr.w);
        f32x2 v = a0 + xp[0];
        f32x2 p2 = __builtin_elementwise_max(v, v * 0.2f) * tp[0];
        v = a1 + xp[1]; p2 += __builtin_elementwise_max(v, v * 0.2f) * tp[1];
        v = a2 + xp[2]; p2 += __builtin_elementwise_max(v, v * 0.2f) * tp[2];
        v = a3 + xp[3]; p2 += __builtin_elementwise_max(v, v * 0.2f) * tp[3];
        float p = p2.x + p2.y;
        DPP_ADD(p, 0xB1);    // xor1 (quad_perm [1,0,3,2])
        DPP_ADD(p, 0x4E);    // xor2 (quad_perm [2,3,0,1])
        DPP_ADD(p, 0x141);   // xor4 (row_half_mirror)
        const float w = __expf(p);
        acc[0] += a0 * w;
        acc[1] += a1 * w;
        acc[2] += a2 * w;
        acc[3] += a3 * w;
        den += w;
    };

    uint4 rcur = make_uint4(0, 0, 0, 0), rnext = rcur;
    if (ns > 0) rcur = *((const uint4*)(xlbase + csr[start + g]) + l);
    if (ns > 1) rnext = *((const uint4*)(xlbase + csr[start + 2 + g]) + l);
    int i = 0;
    for (; i + 2 < ns; i++) {               // steady state: unconditional prefetch
        const uint4 r2 = *((const uint4*)(xlbase + csr[start + 2 * (i + 2) + g]) + l);
        body(rcur);
        rcur = rnext; rnext = r2;
    }
    for (; i < ns; i++) {                   // epilogue (<=2 iterations)
        body(rcur);
        rcur = rnext;
    }
    // combine across the 2 slots (lane <-> lane^32 hold the same elems)
    den += __shfl_xor(den, 32);
    const float inv = 1.f / (den + 1e-16f);
#pragma unroll
    for (int c = 0; c < 4; c++) {
        f32x2 t2 = acc[c];
        t2.x += __shfl_xor(t2.x, 32);
        t2.y += __shfl_xor(t2.y, 32);
        acc[c] = t2;
    }
    const float4 ba = ((const float4*)b1)[2 * l];
    const float4 bb = ((const float4*)b1)[2 * l + 1];
    f32x2 bp[4];
    bp[0] = (f32x2){ba.x, ba.y}; bp[1] = (f32x2){ba.z, ba.w};
    bp[2] = (f32x2){bb.x, bb.y}; bp[3] = (f32x2){bb.z, bb.w};
    float o[8];
#pragma unroll
    for (int c = 0; c < 4; c++) {
        f32x2 t2 = acc[c] * inv + bp[c];
        o[2 * c]     = t2.x > 0.f ? t2.x : expm1f(t2.x);
        o[2 * c + 1] = t2.y > 0.f ? t2.y : expm1f(t2.y);
    }
    if (g == 0) {
        uint4 u;
        u.x = pack2bf(o[0], o[1]);
        u.y = pack2bf(o[2], o[3]);
        u.z = pack2bf(o[4], o[5]);
        u.w = pack2bf(o[6], o[7]);
        h1b[(long)node * 32 + l] = u;
    }
}

// ==== K6: layer-2 MFMA projection: h1(bf16)[N,256] @ [W2l|W2r] ==============
__global__ __launch_bounds__(256) void k_gemm2(const uint4* __restrict__ h,   // bf16 rows
                                               const unsigned short* __restrict__ Wt2,
                                               unsigned short* __restrict__ xlb,
                                               unsigned short* __restrict__ xrb) {
    __shared__ unsigned short sA[64 * 264];
    const int t = threadIdx.x;
    const int lane = t & 63, wv = t >> 6;
    const int m0 = blockIdx.x * 64;
#pragma unroll
    for (int j = 0; j < 8; j++) {
        const int i8 = t + j * 256;          // 0..2047, 8 shorts each
        const int row = i8 >> 5, c8 = i8 & 31;
        uint4 v = make_uint4(0, 0, 0, 0);
        if (m0 + row < N_NODES) v = h[(long)(m0 + row) * 32 + c8];
        *(uint4*)&sA[row * 264 + c8 * 8] = v;
    }
    __syncthreads();
    const int l15 = lane & 15, quad = lane >> 4;
    const int ncol0 = wv * 32;
    short8 b[2][8];
#pragma unroll
    for (int nt = 0; nt < 2; nt++)
#pragma unroll
        for (int ks = 0; ks < 8; ks++)
            b[nt][ks] = *(const short8*)&Wt2[(ncol0 + nt * 16 + l15) * 256 + ks * 32 + quad * 8];
    for (int mt = 0; mt < 4; mt++) {
        floatx4 acc[2];
        acc[0] = (floatx4)(0.f);
        acc[1] = (floatx4)(0.f);
#pragma unroll
        for (int ks = 0; ks < 8; ks++) {
            const short8 a = *(const short8*)&sA[(mt * 16 + l15) * 264 + ks * 32 + quad * 8];
            acc[0] = __builtin_amdgcn_mfma_f32_16x16x32_bf16(a, b[0][ks], acc[0], 0, 0, 0);
            acc[1] = __builtin_amdgcn_mfma_f32_16x16x32_bf16(a, b[1][ks], acc[1], 0, 0, 0);
        }
        const int mrow0 = m0 + mt * 16 + quad * 4;
#pragma unroll
        for (int nt = 0; nt < 2; nt++) {
            const int n = ncol0 + nt * 16 + l15;
#pragma unroll
            for (int r = 0; r < 4; r++) {
                const int m = mrow0 + r;
                if (m < N_NODES) {
                    if (n < 64) xlb[(long)m * 64 + n] = f2bf(acc[nt][r]);
                    else        xrb[(long)m * 64 + (n - 64)] = f2bf(acc[nt][r]);
                }
            }
        }
    }
}

// ==== K7: layer-2 fused node kernel: 4 edge-slots x 16 lanes, DPP reduce ====
__global__ __launch_bounds__(256) void k_node2(const int* __restrict__ rowstart,
                                               const int* __restrict__ deg,
                                               const int* __restrict__ csr,
                                               const uint2* __restrict__ xlb,   // bf16 row = 16 uint2
                                               const uint2* __restrict__ xrb,   // bf16 row = 16 uint2
                                               const float* __restrict__ att,
                                               const float* __restrict__ b2,
                                               const float* __restrict__ Wlin,
                                               const float* __restrict__ blin,
                                               float* __restrict__ out) {
    __shared__ float sh[4][64];
    const int lane = threadIdx.x & 63;
    const int wv = threadIdx.x >> 6;
    const int node = blockIdx.x * 4 + wv;   // 50000 % 4 == 0
    const int g = lane >> 4;                // edge slot (0..3)
    const int l = lane & 15;                // covers elems 4l..4l+3
    const char* xlbase = (const char*)xlb;
    const uint2 xru = xrb[(long)node * 16 + l];
    const float4 at4 = ((const float4*)att)[l];
    f32x2 xp[2], tp[2];
    xp[0] = (f32x2){bf_lo(xru.x), bf_hi(xru.x)};
    xp[1] = (f32x2){bf_lo(xru.y), bf_hi(xru.y)};
    tp[0] = (f32x2){at4.x, at4.y}; tp[1] = (f32x2){at4.z, at4.w};
    const int start = rowstart[node];
    const int cnt = deg[node];
    const int ns = (cnt - g + 3) >> 2;      // my slot's edge count (edges 4i+g)
    float den = 0.f;
    f32x2 acc[2];
    acc[0] = (f32x2)(0.f); acc[1] = (f32x2)(0.f);

    auto body = [&](const uint2& rr) {
        f32x2 a0, a1;
        a0.x = bf_lo(rr.x); a0.y = bf_hi(rr.x);
        a1.x = bf_lo(rr.y); a1.y = bf_hi(rr.y);
        f32x2 v = a0 + xp[0];
        f32x2 p2 = __builtin_elementwise_max(v, v * 0.2f) * tp[0];
        v = a1 + xp[1]; p2 += __builtin_elementwise_max(v, v * 0.2f) * tp[1];
        float p = p2.x + p2.y;
        DPP_ADD(p, 0xB1);    // xor1
        DPP_ADD(p, 0x4E);    // xor2
        DPP_ADD(p, 0x141);   // xor4 (row_half_mirror)
        DPP_ADD(p, 0x140);   // xor8 (row_mirror)
        const float w = __expf(p);
        acc[0] += a0 * w;
        acc[1] += a1 * w;
        den += w;
    };

    uint2 rcur = make_uint2(0, 0), rnext = rcur;
    if (ns > 0) rcur = *((const uint2*)(xlbase + (csr[start + g] >> 2)) + l);
    if (ns > 1) rnext = *((const uint2*)(xlbase + (csr[start + 4 + g] >> 2)) + l);
    int i = 0;
    for (; i + 2 < ns; i++) {
        const uint2 r2 = *((const uint2*)(xlbase + (csr[start + 4 * (i + 2) + g] >> 2)) + l);
        body(rcur);
        rcur = rnext; rnext = r2;
    }
    for (; i < ns; i++) {
        body(rcur);
        rcur = rnext;
    }
    // combine across 4 slots (xor 16 then xor 32 align same elems)
    den += __shfl_xor(den, 16);
    den += __shfl_xor(den, 32);
    const float inv = 1.f / (den + 1e-16f);
    float t0 = acc[0].x, t1 = acc[0].y, t2 = acc[1].x, t3 = acc[1].y;
    t0 += __shfl_xor(t0, 16); t0 += __shfl_xor(t0, 32);
    t1 += __shfl_xor(t1, 16); t1 += __shfl_xor(t1, 32);
    t2 += __shfl_xor(t2, 16); t2 += __shfl_xor(t2, 32);
    t3 += __shfl_xor(t3, 16); t3 += __shfl_xor(t3, 32);
    const float4 b4 = ((const float4*)b2)[l];
    float4 h4;
    h4.x = t0 * inv + b4.x; h4.x = h4.x > 0.f ? h4.x : expm1f(h4.x);
    h4.y = t1 * inv + b4.y; h4.y = h4.y > 0.f ? h4.y : expm1f(h4.y);
    h4.z = t2 * inv + b4.z; h4.z = h4.z > 0.f ? h4.z : expm1f(h4.z);
    h4.w = t3 * inv + b4.w; h4.w = h4.w > 0.f ? h4.w : expm1f(h4.w);
    if (g == 0) ((float4*)sh[wv])[l] = h4;
    __syncthreads();
    float o = blin[lane];
#pragma unroll
    for (int k = 0; k < 64; k++) o = fmaf(sh[wv][k], Wlin[k * 64 + lane], o);
    out[(long)node * 64 + lane] = o;
}

extern "C" void kernel_launch(void* const* d_in, const int* in_sizes, int n_in,
                              void* d_out, int out_size, void* d_ws, size_t ws_size,
                              hipStream_t stream) {
    (void)in_sizes; (void)n_in; (void)out_size; (void)ws_size;
    const float* x    = (const float*)d_in[0];
    const int*   ei   = (const int*)d_in[1];
    const float* W1l  = (const float*)d_in[2];
    const float* W1r  = (const float*)d_in[3];
    const float* att1 = (const float*)d_in[4];
    const float* b1   = (const float*)d_in[5];
    const float* W2l  = (const float*)d_in[6];
    const float* W2r  = (const float*)d_in[7];
    const float* att2 = (const float*)d_in[8];
    const float* b2   = (const float*)d_in[9];
    const float* Wlin = (const float*)d_in[10];
    const float* blin = (const float*)d_in[11];

    float* ws = (float*)d_ws;
    unsigned short* XL1b = (unsigned short*)(ws);              // [N,256] bf16 (6.4M floats)
    unsigned short* XR1b = (unsigned short*)(ws + 6400000);    // [N,256] bf16
    uint4*          H1b  = (uint4*)(ws + 12800000);            // [N,256] bf16
    unsigned short* XL2b = (unsigned short*)(ws + 19200000);   // [N,64] bf16
    unsigned short* XR2b = (unsigned short*)(ws + 20800000);   // [N,64] bf16
    int* deg      = (int*)(ws + 22400000);  // 50,000
    int* rowstart = deg + 50000;            // 50,000
    int* cursor   = rowstart + 50000;       // 50,000
    int* blocksum = cursor + 50000;         // 256
    int* blockoff = blocksum + 256;         // 256
    int* csr      = blockoff + 256;         // 850,000 -> ends ~23,400,512 floats
    unsigned short* Wt1 = (unsigned short*)(ws + 23500000);    // 65,536 shorts -> ends 23,532,768
    unsigned short* Wt2 = (unsigned short*)(ws + 23550000);    // 32,768 shorts (clear of Wt1)

    // K1: weight prep + zero deg
    k_prep<<<580, 256, 0, stream>>>(W1l, W1r, W2l, W2r, Wt1, Wt2, deg);
    // K2: gemm1 (782 blocks) fused with dst histogram (1024 blocks)
    k_g1h<<<1806, 256, 0, stream>>>(x, Wt1, XL1b, XR1b, ei, deg);
    // K3: 3-pass parallel scan -> rowstart + cursor
    k_scan1<<<NB_SCAN, 256, 0, stream>>>(deg, rowstart, blocksum);
    k_scan2<<<1, 256, 0, stream>>>(blocksum, blockoff);
    k_scan3<<<NB_SCAN, 256, 0, stream>>>(rowstart, blockoff, cursor);
    // K4: scatter byte offsets into CSR
    k_scatter<<<(ETOT + 255) / 256, 256, 0, stream>>>(ei, cursor, csr);
    // K5: layer-1 fused attention
    k_node1<<<12500, 256, 0, stream>>>(rowstart, deg, csr,
                                       (const uint4*)XL1b, (const uint4*)XR1b,
                                       att1, b1, H1b);
    // K6: layer-2 projection
    k_gemm2<<<782, 256, 0, stream>>>((const uint4*)H1b, Wt2, XL2b, XR2b);
    // K7: layer-2 fused attention + linear
    k_node2<<<12500, 256, 0, stream>>>(rowstart, deg, csr,
                                       (const uint2*)XL2b, (const uint2*)XR2b,
                                       att2, b2, Wlin, blin, (float*)d_out);
}

// Round 12
// 309.702 us; speedup vs baseline: 1.2364x; 1.0763x over previous
//
#include <hip/hip_runtime.h>
#include <hip/hip_bf16.h>
#include <math.h>

#define N_NODES 50000
#define N_EDGES 800000
#define ETOT (N_EDGES + N_NODES)   // 850000 with self loops
#define NB_SCAN 196                // ceil(50000/256)

typedef __attribute__((ext_vector_type(8))) short short8;      // 8 bf16 (4 VGPRs)
typedef __attribute__((ext_vector_type(4))) float floatx4;
typedef __attribute__((ext_vector_type(2))) float f32x2;       // -> v_pk_* f32 ops

// bf16 (raw u16 pairs) -> f32 decode: 1 VALU op each
__device__ __forceinline__ float bf_lo(unsigned u) { return __uint_as_float(u << 16); }
__device__ __forceinline__ float bf_hi(unsigned u) { return __uint_as_float(u & 0xffff0000u); }
// f32 -> bf16 raw bits, RNE
__device__ __forceinline__ unsigned short f2bf(float f) {
    unsigned u = __float_as_uint(f);
    return (unsigned short)((u + 0x7fffu + ((u >> 16) & 1u)) >> 16);
}
__device__ __forceinline__ unsigned pack2bf(float a, float b) {
    return (unsigned)f2bf(a) | ((unsigned)f2bf(b) << 16);
}
// butterfly add via DPP (VALU pipe, no LDS): ctrl must be a literal
#define DPP_ADD(p, ctrl) \
    (p) += __int_as_float(__builtin_amdgcn_update_dpp(0, __float_as_int(p), (ctrl), 0xF, 0xF, true))

// ==== K1: weight prep (bf16 transpose/concat, incl. Wlin) + zero deg ========
__global__ __launch_bounds__(256) void k_prep(const float* __restrict__ W1l,
                                              const float* __restrict__ W1r,
                                              const float* __restrict__ W2l,
                                              const float* __restrict__ W2r,
                                              const float* __restrict__ Wlin,
                                              unsigned short* __restrict__ Wt1,
                                              unsigned short* __restrict__ Wt2,
                                              unsigned short* __restrict__ Wt3,
                                              int* __restrict__ deg) {
    const int b = blockIdx.x;
    if (b < 400) {
        const int idx = b * 256 + threadIdx.x;
        if (idx < 65536) {
            const int k = idx >> 9;          // 0..127
            const int n = idx & 511;         // 0..511
            const float v = (n < 256) ? W1l[k * 256 + n] : W1r[k * 256 + (n - 256)];
            Wt1[n * 128 + k] = f2bf(v);
        } else if (idx < 98304) {
            const int j = idx - 65536;       // 0..32767
            const int k = j >> 7;            // 0..255
            const int n = j & 127;           // 0..127
            const float v = (n < 64) ? W2l[k * 64 + n] : W2r[k * 64 + (n - 64)];
            Wt2[n * 256 + k] = f2bf(v);
        } else {
            const int j = idx - 98304;       // 0..4095
            const int n = j >> 6, k = j & 63;
            Wt3[n * 64 + k] = f2bf(Wlin[k * 64 + n]);
        }
    } else {
        const int i = (b - 400) * 256 + threadIdx.x;
        if (i < N_NODES) deg[i] = 0;
    }
}

// ==== K2: fused layer-1 MFMA projection (782 blocks) + dst histogram ========
__global__ __launch_bounds__(256) void k_g1h(const float* __restrict__ x,
                                             const unsigned short* __restrict__ Wt1,
                                             unsigned short* __restrict__ xlb,
                                             unsigned short* __restrict__ xrb,
                                             const int* __restrict__ ei,
                                             int* __restrict__ deg) {
    __shared__ unsigned short sA[128 * 136];
    const int b = blockIdx.x;
    if (b >= 782) {   // histogram path, grid-stride
        for (long e = (long)(b - 782) * 256 + threadIdx.x; e < ETOT; e += 1024 * 256) {
            const int d = (e < N_EDGES) ? ei[N_EDGES + e] : (int)(e - N_EDGES);
            atomicAdd(&deg[d], 1);
        }
        return;
    }
    const int t = threadIdx.x;
    const int lane = t & 63, wv = t >> 6;
    const int m0 = (b >> 1) * 128;
    const int flavor = b & 1;
#pragma unroll
    for (int j = 0; j < 16; j++) {
        const int i4 = t + j * 256;
        const int row = i4 >> 5, k4 = i4 & 31;
        float4 v = make_float4(0.f, 0.f, 0.f, 0.f);
        if (m0 + row < N_NODES) v = ((const float4*)x)[(long)(m0 + row) * 32 + k4];
        ushort4 u;
        u.x = f2bf(v.x); u.y = f2bf(v.y); u.z = f2bf(v.z); u.w = f2bf(v.w);
        *(ushort4*)&sA[row * 136 + k4 * 4] = u;
    }
    __syncthreads();
    const int l15 = lane & 15, quad = lane >> 4;
    const int nloc0 = wv * 64;
    unsigned short* outp = flavor ? xrb : xlb;
    short8 bfr[4][4];
#pragma unroll
    for (int nt = 0; nt < 4; nt++)
#pragma unroll
        for (int ks = 0; ks < 4; ks++)
            bfr[nt][ks] = *(const short8*)&Wt1[(flavor * 256 + nloc0 + nt * 16 + l15) * 128 + ks * 32 + quad * 8];
    for (int mt = 0; mt < 8; mt++) {
        short8 a[4];
#pragma unroll
        for (int ks = 0; ks < 4; ks++)
            a[ks] = *(const short8*)&sA[(mt * 16 + l15) * 136 + ks * 32 + quad * 8];
        floatx4 acc[4];
#pragma unroll
        for (int nt = 0; nt < 4; nt++) {
            acc[nt] = (floatx4)(0.f);
#pragma unroll
            for (int ks = 0; ks < 4; ks++)
                acc[nt] = __builtin_amdgcn_mfma_f32_16x16x32_bf16(a[ks], bfr[nt][ks], acc[nt], 0, 0, 0);
        }
        const int mrow0 = m0 + mt * 16 + quad * 4;
#pragma unroll
        for (int nt = 0; nt < 4; nt++) {
            const int n = nloc0 + nt * 16 + l15;
#pragma unroll
            for (int r = 0; r < 4; r++) {
                const int m = mrow0 + r;
                if (m < N_NODES) outp[(long)m * 256 + n] = f2bf(acc[nt][r]);
            }
        }
    }
}

// ==== K3a/b/c: 3-pass parallel exclusive scan ===============================
__global__ __launch_bounds__(256) void k_scan1(const int* __restrict__ deg,
                                               int* __restrict__ rowstart,
                                               int* __restrict__ blocksum) {
    __shared__ int wsum[4];
    const int t = threadIdx.x, lane = t & 63, wv = t >> 6;
    const int i = blockIdx.x * 256 + t;
    const int v = (i < N_NODES) ? deg[i] : 0;
    int incl = v;
#pragma unroll
    for (int off = 1; off < 64; off <<= 1) {
        const int u = __shfl_up(incl, off);
        if (lane >= off) incl += u;
    }
    if (lane == 63) wsum[wv] = incl;
    __syncthreads();
    int woff = 0;
#pragma unroll
    for (int j = 0; j < 4; j++) woff += (j < wv) ? wsum[j] : 0;
    const int excl = incl - v + woff;
    if (i < N_NODES) rowstart[i] = excl;
    if (t == 255) blocksum[blockIdx.x] = excl + v;
}

__global__ __launch_bounds__(256) void k_scan2(const int* __restrict__ blocksum,
                                               int* __restrict__ blockoff) {
    __shared__ int wsum[4];
    const int t = threadIdx.x, lane = t & 63, wv = t >> 6;
    const int v = (t < NB_SCAN) ? blocksum[t] : 0;
    int incl = v;
#pragma unroll
    for (int off = 1; off < 64; off <<= 1) {
        const int u = __shfl_up(incl, off);
        if (lane >= off) incl += u;
    }
    if (lane == 63) wsum[wv] = incl;
    __syncthreads();
    int woff = 0;
#pragma unroll
    for (int j = 0; j < 4; j++) woff += (j < wv) ? wsum[j] : 0;
    if (t < NB_SCAN) blockoff[t] = incl - v + woff;
}

__global__ __launch_bounds__(256) void k_scan3(int* __restrict__ rowstart,
                                               const int* __restrict__ blockoff,
                                               int* __restrict__ cursor) {
    const int i = blockIdx.x * 256 + threadIdx.x;
    if (i < N_NODES) {
        const int r = rowstart[i] + blockoff[blockIdx.x];
        rowstart[i] = r;
        cursor[i] = r;
    }
}

// ==== K4: scatter BYTE OFFSETS (s*512) into dst-grouped CSR slots ===========
__global__ __launch_bounds__(256) void k_scatter(const int* __restrict__ ei,
                                                 int* __restrict__ cursor,
                                                 int* __restrict__ csr) {
    const long e = (long)blockIdx.x * 256 + threadIdx.x;
    if (e >= ETOT) return;
    int s, d;
    if (e < N_EDGES) { s = ei[e]; d = ei[N_EDGES + e]; }
    else { s = d = (int)(e - N_EDGES); }
    const int pos = atomicAdd(&cursor[d], 1);
    csr[pos] = s << 9;   // byte offset into 512B bf16 rows (layer1); layer2 = >>2
}

// ==== K5: layer-1 fused node kernel: 2 edge-slots x 32 lanes, DPP reduce ====
__global__ __launch_bounds__(256) void k_node1(const int* __restrict__ rowstart,
                                               const int* __restrict__ deg,
                                               const int* __restrict__ csr,
                                               const uint4* __restrict__ xlb,   // bf16 row = 32 uint4
                                               const uint4* __restrict__ xrb,   // bf16 row = 32 uint4
                                               const float* __restrict__ att,   // [256]
                                               const float* __restrict__ b1,
                                               uint4* __restrict__ h1b) {      // bf16 row = 32 uint4
    const int lane = threadIdx.x & 63;
    const int wv = threadIdx.x >> 6;
    const int node = blockIdx.x * 4 + wv;   // 50000 % 4 == 0
    const int g = lane >> 5;                // edge slot
    const int l = lane & 31;                // covers elems 8l..8l+7
    const char* xlbase = (const char*)xlb;
    const uint4 xru = xrb[(long)node * 32 + l];
    const float4 ta = ((const float4*)att)[2 * l];
    const float4 tb = ((const float4*)att)[2 * l + 1];
    f32x2 xp[4], tp[4];
    xp[0] = (f32x2){bf_lo(xru.x), bf_hi(xru.x)};
    xp[1] = (f32x2){bf_lo(xru.y), bf_hi(xru.y)};
    xp[2] = (f32x2){bf_lo(xru.z), bf_hi(xru.z)};
    xp[3] = (f32x2){bf_lo(xru.w), bf_hi(xru.w)};
    tp[0] = (f32x2){ta.x, ta.y}; tp[1] = (f32x2){ta.z, ta.w};
    tp[2] = (f32x2){tb.x, tb.y}; tp[3] = (f32x2){tb.z, tb.w};
    const int start = rowstart[node];
    const int cnt = deg[node];
    const int ns = (cnt - g + 1) >> 1;      // my slot's edge count
    float den = 0.f;
    f32x2 acc[4];
#pragma unroll
    for (int c = 0; c < 4; c++) acc[c] = (f32x2)(0.f);

    auto body = [&](const uint4& rr) {
        f32x2 a0, a1, a2, a3;
        a0.x = bf_lo(rr.x); a0.y = bf_hi(rr.x);
        a1.x = bf_lo(rr.y); a1.y = bf_hi(rr.y);
        a2.x = bf_lo(rr.z); a2.y = bf_hi(rr.z);
        a3.x = bf_lo(rr.w); a3.y = bf_hi(rr.w);
        f32x2 v = a0 + xp[0];
        f32x2 p2 = __builtin_elementwise_max(v, v * 0.2f) * tp[0];
        v = a1 + xp[1]; p2 += __builtin_elementwise_max(v, v * 0.2f) * tp[1];
        v = a2 + xp[2]; p2 += __builtin_elementwise_max(v, v * 0.2f) * tp[2];
        v = a3 + xp[3]; p2 += __builtin_elementwise_max(v, v * 0.2f) * tp[3];
        float p = p2.x + p2.y;
        DPP_ADD(p, 0xB1);    // xor1 (quad_perm [1,0,3,2])
        DPP_ADD(p, 0x4E);    // xor2 (quad_perm [2,3,0,1])
        DPP_ADD(p, 0x141);   // xor4 (row_half_mirror)
        const float w = __expf(p);
        acc[0] += a0 * w;
        acc[1] += a1 * w;
        acc[2] += a2 * w;
        acc[3] += a3 * w;
        den += w;
    };

    uint4 rcur = make_uint4(0, 0, 0, 0), rnext = rcur;
    if (ns > 0) rcur = *((const uint4*)(xlbase + csr[start + g]) + l);
    if (ns > 1) rnext = *((const uint4*)(xlbase + csr[start + 2 + g]) + l);
    int i = 0;
    for (; i + 2 < ns; i++) {               // steady state: unconditional prefetch
        const uint4 r2 = *((const uint4*)(xlbase + csr[start + 2 * (i + 2) + g]) + l);
        body(rcur);
        rcur = rnext; rnext = r2;
    }
    for (; i < ns; i++) {                   // epilogue (<=2 iterations)
        body(rcur);
        rcur = rnext;
    }
    // combine across the 2 slots (lane <-> lane^32 hold the same elems)
    den += __shfl_xor(den, 32);
    const float inv = 1.f / (den + 1e-16f);
#pragma unroll
    for (int c = 0; c < 4; c++) {
        f32x2 t2 = acc[c];
        t2.x += __shfl_xor(t2.x, 32);
        t2.y += __shfl_xor(t2.y, 32);
        acc[c] = t2;
    }
    const float4 ba = ((const float4*)b1)[2 * l];
    const float4 bb = ((const float4*)b1)[2 * l + 1];
    f32x2 bp[4];
    bp[0] = (f32x2){ba.x, ba.y}; bp[1] = (f32x2){ba.z, ba.w};
    bp[2] = (f32x2){bb.x, bb.y}; bp[3] = (f32x2){bb.z, bb.w};
    float o[8];
#pragma unroll
    for (int c = 0; c < 4; c++) {
        f32x2 t2 = acc[c] * inv + bp[c];
        o[2 * c]     = t2.x > 0.f ? t2.x : expm1f(t2.x);
        o[2 * c + 1] = t2.y > 0.f ? t2.y : expm1f(t2.y);
    }
    if (g == 0) {
        uint4 u;
        u.x = pack2bf(o[0], o[1]);
        u.y = pack2bf(o[2], o[3]);
        u.z = pack2bf(o[4], o[5]);
        u.w = pack2bf(o[6], o[7]);
        h1b[(long)node * 32 + l] = u;
    }
}

// ==== K6: layer-2 MFMA projection: h1(bf16)[N,256] @ [W2l|W2r] ==============
__global__ __launch_bounds__(256) void k_gemm2(const uint4* __restrict__ h,   // bf16 rows
                                               const unsigned short* __restrict__ Wt2,
                                               unsigned short* __restrict__ xlb,
                                               unsigned short* __restrict__ xrb) {
    __shared__ unsigned short sA[64 * 264];
    const int t = threadIdx.x;
    const int lane = t & 63, wv = t >> 6;
    const int m0 = blockIdx.x * 64;
#pragma unroll
    for (int j = 0; j < 8; j++) {
        const int i8 = t + j * 256;          // 0..2047, 8 shorts each
        const int row = i8 >> 5, c8 = i8 & 31;
        uint4 v = make_uint4(0, 0, 0, 0);
        if (m0 + row < N_NODES) v = h[(long)(m0 + row) * 32 + c8];
        *(uint4*)&sA[row * 264 + c8 * 8] = v;
    }
    __syncthreads();
    const int l15 = lane & 15, quad = lane >> 4;
    const int ncol0 = wv * 32;
    short8 b[2][8];
#pragma unroll
    for (int nt = 0; nt < 2; nt++)
#pragma unroll
        for (int ks = 0; ks < 8; ks++)
            b[nt][ks] = *(const short8*)&Wt2[(ncol0 + nt * 16 + l15) * 256 + ks * 32 + quad * 8];
    for (int mt = 0; mt < 4; mt++) {
        floatx4 acc[2];
        acc[0] = (floatx4)(0.f);
        acc[1] = (floatx4)(0.f);
#pragma unroll
        for (int ks = 0; ks < 8; ks++) {
            const short8 a = *(const short8*)&sA[(mt * 16 + l15) * 264 + ks * 32 + quad * 8];
            acc[0] = __builtin_amdgcn_mfma_f32_16x16x32_bf16(a, b[0][ks], acc[0], 0, 0, 0);
            acc[1] = __builtin_amdgcn_mfma_f32_16x16x32_bf16(a, b[1][ks], acc[1], 0, 0, 0);
        }
        const int mrow0 = m0 + mt * 16 + quad * 4;
#pragma unroll
        for (int nt = 0; nt < 2; nt++) {
            const int n = ncol0 + nt * 16 + l15;
#pragma unroll
            for (int r = 0; r < 4; r++) {
                const int m = mrow0 + r;
                if (m < N_NODES) {
                    if (n < 64) xlb[(long)m * 64 + n] = f2bf(acc[nt][r]);
                    else        xrb[(long)m * 64 + (n - 64)] = f2bf(acc[nt][r]);
                }
            }
        }
    }
}

// ==== K7: layer-2 fused node kernel: 4 edge-slots x 16 lanes, DPP reduce ====
// Writes ELU'd h2 as bf16; final linear moved to k_gemm3 (MFMA).
__global__ __launch_bounds__(256) void k_node2(const int* __restrict__ rowstart,
                                               const int* __restrict__ deg,
                                               const int* __restrict__ csr,
                                               const uint2* __restrict__ xlb,   // bf16 row = 16 uint2
                                               const uint2* __restrict__ xrb,   // bf16 row = 16 uint2
                                               const float* __restrict__ att,
                                               const float* __restrict__ b2,
                                               uint2* __restrict__ h2b) {      // bf16 row = 16 uint2
    const int lane = threadIdx.x & 63;
    const int wv = threadIdx.x >> 6;
    const int node = blockIdx.x * 4 + wv;   // 50000 % 4 == 0
    const int g = lane >> 4;                // edge slot (0..3)
    const int l = lane & 15;                // covers elems 4l..4l+3
    const char* xlbase = (const char*)xlb;
    const uint2 xru = xrb[(long)node * 16 + l];
    const float4 at4 = ((const float4*)att)[l];
    f32x2 xp[2], tp[2];
    xp[0] = (f32x2){bf_lo(xru.x), bf_hi(xru.x)};
    xp[1] = (f32x2){bf_lo(xru.y), bf_hi(xru.y)};
    tp[0] = (f32x2){at4.x, at4.y}; tp[1] = (f32x2){at4.z, at4.w};
    const int start = rowstart[node];
    const int cnt = deg[node];
    const int ns = (cnt - g + 3) >> 2;      // my slot's edge count (edges 4i+g)
    float den = 0.f;
    f32x2 acc[2];
    acc[0] = (f32x2)(0.f); acc[1] = (f32x2)(0.f);

    auto body = [&](const uint2& rr) {
        f32x2 a0, a1;
        a0.x = bf_lo(rr.x); a0.y = bf_hi(rr.x);
        a1.x = bf_lo(rr.y); a1.y = bf_hi(rr.y);
        f32x2 v = a0 + xp[0];
        f32x2 p2 = __builtin_elementwise_max(v, v * 0.2f) * tp[0];
        v = a1 + xp[1]; p2 += __builtin_elementwise_max(v, v * 0.2f) * tp[1];
        float p = p2.x + p2.y;
        DPP_ADD(p, 0xB1);    // xor1
        DPP_ADD(p, 0x4E);    // xor2
        DPP_ADD(p, 0x141);   // xor4 (row_half_mirror)
        DPP_ADD(p, 0x140);   // xor8 (row_mirror)
        const float w = __expf(p);
        acc[0] += a0 * w;
        acc[1] += a1 * w;
        den += w;
    };

    uint2 rcur = make_uint2(0, 0), rnext = rcur;
    if (ns > 0) rcur = *((const uint2*)(xlbase + (csr[start + g] >> 2)) + l);
    if (ns > 1) rnext = *((const uint2*)(xlbase + (csr[start + 4 + g] >> 2)) + l);
    int i = 0;
    for (; i + 2 < ns; i++) {
        const uint2 r2 = *((const uint2*)(xlbase + (csr[start + 4 * (i + 2) + g] >> 2)) + l);
        body(rcur);
        rcur = rnext; rnext = r2;
    }
    for (; i < ns; i++) {
        body(rcur);
        rcur = rnext;
    }
    // combine across 4 slots (xor 16 then xor 32 align same elems)
    den += __shfl_xor(den, 16);
    den += __shfl_xor(den, 32);
    const float inv = 1.f / (den + 1e-16f);
    float t0 = acc[0].x, t1 = acc[0].y, t2 = acc[1].x, t3 = acc[1].y;
    t0 += __shfl_xor(t0, 16); t0 += __shfl_xor(t0, 32);
    t1 += __shfl_xor(t1, 16); t1 += __shfl_xor(t1, 32);
    t2 += __shfl_xor(t2, 16); t2 += __shfl_xor(t2, 32);
    t3 += __shfl_xor(t3, 16); t3 += __shfl_xor(t3, 32);
    const float4 b4 = ((const float4*)b2)[l];
    float4 h4;
    h4.x = t0 * inv + b4.x; h4.x = h4.x > 0.f ? h4.x : expm1f(h4.x);
    h4.y = t1 * inv + b4.y; h4.y = h4.y > 0.f ? h4.y : expm1f(h4.y);
    h4.z = t2 * inv + b4.z; h4.z = h4.z > 0.f ? h4.z : expm1f(h4.z);
    h4.w = t3 * inv + b4.w; h4.w = h4.w > 0.f ? h4.w : expm1f(h4.w);
    if (g == 0) {
        uint2 u;
        u.x = pack2bf(h4.x, h4.y);
        u.y = pack2bf(h4.z, h4.w);
        h2b[(long)node * 16 + l] = u;
    }
}

// ==== K8: final linear via MFMA: h2(bf16)[N,64] @ Wlin[64,64] + blin ========
__global__ __launch_bounds__(256) void k_gemm3(const uint4* __restrict__ h2,  // bf16 rows = 8 uint4
                                               const unsigned short* __restrict__ Wt3, // [64][64] n-major
                                               const float* __restrict__ blin,
                                               float* __restrict__ out) {
    __shared__ unsigned short sA[64 * 72];   // 64 rows, stride 72 shorts (144B, 16B aligned)
    const int t = threadIdx.x;
    const int lane = t & 63, wv = t >> 6;
    const int m0 = blockIdx.x * 64;
#pragma unroll
    for (int j = 0; j < 2; j++) {
        const int i8 = t + j * 256;          // uint4 index; row = i8>>3, c8 = i8&7
        const int row = i8 >> 3, c8 = i8 & 7;
        uint4 v = make_uint4(0, 0, 0, 0);
        if (m0 + row < N_NODES) v = h2[(long)(m0 + row) * 8 + c8];
        *(uint4*)&sA[row * 72 + c8 * 8] = v;
    }
    __syncthreads();
    const int l15 = lane & 15, quad = lane >> 4;
    const int n0 = wv * 16;
    const short8 b0 = *(const short8*)&Wt3[(n0 + l15) * 64 + quad * 8];
    const short8 b1 = *(const short8*)&Wt3[(n0 + l15) * 64 + 32 + quad * 8];
    const float bl = blin[n0 + l15];
#pragma unroll
    for (int mt = 0; mt < 4; mt++) {
        const short8 a0 = *(const short8*)&sA[(mt * 16 + l15) * 72 + quad * 8];
        const short8 a1 = *(const short8*)&sA[(mt * 16 + l15) * 72 + 32 + quad * 8];
        floatx4 acc = (floatx4)(0.f);
        acc = __builtin_amdgcn_mfma_f32_16x16x32_bf16(a0, b0, acc, 0, 0, 0);
        acc = __builtin_amdgcn_mfma_f32_16x16x32_bf16(a1, b1, acc, 0, 0, 0);
        const int mrow0 = m0 + mt * 16 + quad * 4;
#pragma unroll
        for (int r = 0; r < 4; r++) {
            const int m = mrow0 + r;
            if (m < N_NODES) out[(long)m * 64 + n0 + l15] = acc[r] + bl;
        }
    }
}

extern "C" void kernel_launch(void* const* d_in, const int* in_sizes, int n_in,
                              void* d_out, int out_size, void* d_ws, size_t ws_size,
                              hipStream_t stream) {
    (void)in_sizes; (void)n_in; (void)out_size; (void)ws_size;
    const float* x    = (const float*)d_in[0];
    const int*   ei   = (const int*)d_in[1];
    const float* W1l  = (const float*)d_in[2];
    const float* W1r  = (const float*)d_in[3];
    const float* att1 = (const float*)d_in[4];
    const float* b1   = (const float*)d_in[5];
    const float* W2l  = (const float*)d_in[6];
    const float* W2r  = (const float*)d_in[7];
    const float* att2 = (const float*)d_in[8];
    const float* b2   = (const float*)d_in[9];
    const float* Wlin = (const float*)d_in[10];
    const float* blin = (const float*)d_in[11];

    float* ws = (float*)d_ws;
    unsigned short* XL1b = (unsigned short*)(ws);              // [N,256] bf16 (6.4M floats)
    uint2*          H2b  = (uint2*)(ws);                       // [N,64] bf16 — overlays XL1b (dead after node1)
    unsigned short* XR1b = (unsigned short*)(ws + 6400000);    // [N,256] bf16
    uint4*          H1b  = (uint4*)(ws + 12800000);            // [N,256] bf16
    unsigned short* XL2b = (unsigned short*)(ws + 19200000);   // [N,64] bf16
    unsigned short* XR2b = (unsigned short*)(ws + 20800000);   // [N,64] bf16
    int* deg      = (int*)(ws + 22400000);  // 50,000
    int* rowstart = deg + 50000;            // 50,000
    int* cursor   = rowstart + 50000;       // 50,000
    int* blocksum = cursor + 50000;         // 256
    int* blockoff = blocksum + 256;         // 256
    int* csr      = blockoff + 256;         // 850,000 -> ends ~23,400,512 floats
    unsigned short* Wt1 = (unsigned short*)(ws + 23500000);    // 65,536 shorts -> ends 23,532,768
    unsigned short* Wt2 = (unsigned short*)(ws + 23550000);    // 32,768 shorts -> ends 23,566,384
    unsigned short* Wt3 = (unsigned short*)(ws + 23600000);    // 4,096 shorts

    // K1: weight prep + zero deg
    k_prep<<<596, 256, 0, stream>>>(W1l, W1r, W2l, W2r, Wlin, Wt1, Wt2, Wt3, deg);
    // K2: gemm1 (782 blocks) fused with dst histogram (1024 blocks)
    k_g1h<<<1806, 256, 0, stream>>>(x, Wt1, XL1b, XR1b, ei, deg);
    // K3: 3-pass parallel scan -> rowstart + cursor
    k_scan1<<<NB_SCAN, 256, 0, stream>>>(deg, rowstart, blocksum);
    k_scan2<<<1, 256, 0, stream>>>(blocksum, blockoff);
    k_scan3<<<NB_SCAN, 256, 0, stream>>>(rowstart, blockoff, cursor);
    // K4: scatter byte offsets into CSR
    k_scatter<<<(ETOT + 255) / 256, 256, 0, stream>>>(ei, cursor, csr);
    // K5: layer-1 fused attention
    k_node1<<<12500, 256, 0, stream>>>(rowstart, deg, csr,
                                       (const uint4*)XL1b, (const uint4*)XR1b,
                                       att1, b1, H1b);
    // K6: layer-2 projection
    k_gemm2<<<782, 256, 0, stream>>>((const uint4*)H1b, Wt2, XL2b, XR2b);
    // K7: layer-2 fused attention -> h2 bf16
    k_node2<<<12500, 256, 0, stream>>>(rowstart, deg, csr,
                                       (const uint2*)XL2b, (const uint2*)XR2b,
                                       att2, b2, H2b);
    // K8: final linear via MFMA
    k_gemm3<<<782, 256, 0, stream>>>((const uint4*)H2b, Wt3, blin, (float*)d_out);
}